// Round 1
// baseline (765.078 us; speedup 1.0000x reference)
//
#include <hip/hip_runtime.h>
#include <hip/hip_bf16.h>
#include <math.h>

#define NPTS 1000000
#define DIM 64
#define HID 64
#define NPATCH 4096
#define BM 128
#define LDH 72  // padded row stride (bf16 elems): 144B rows, 16B-aligned, bank-friendly

typedef float f32x4 __attribute__((ext_vector_type(4)));
typedef __bf16 bf16x8 __attribute__((ext_vector_type(8)));

// -------- Pass 1: per-patch coordinate sums + counts via global atomics ------
__global__ void patch_accum(const float* __restrict__ coord,
                            const int* __restrict__ ids,
                            float* __restrict__ acc4 /* NPATCH x {sx,sy,sz,cnt} */) {
    int i = blockIdx.x * blockDim.x + threadIdx.x;
    if (i >= NPTS) return;
    int p = ids[i];
    float cx = coord[3 * i + 0];
    float cy = coord[3 * i + 1];
    float cz = coord[3 * i + 2];
    atomicAdd(&acc4[4 * p + 0], cx);
    atomicAdd(&acc4[4 * p + 1], cy);
    atomicAdd(&acc4[4 * p + 2], cz);
    atomicAdd(&acc4[4 * p + 3], 1.0f);
}

// -------- Pass 2: fused MLP + residual + depthwise + pointwise + LayerNorm ---
__global__ __launch_bounds__(256) void cpe_main(
    const float* __restrict__ x, const float* __restrict__ coord,
    const int* __restrict__ ids,
    const float* __restrict__ W1, const float* __restrict__ b1,
    const float* __restrict__ W2, const float* __restrict__ b2,
    const float* __restrict__ dww, const float* __restrict__ dwb,
    const float* __restrict__ pwW, const float* __restrict__ pwb,
    const float* __restrict__ lng, const float* __restrict__ lnb,
    const float* __restrict__ acc4, float* __restrict__ out) {

    __shared__ __align__(16) __bf16 sW2t[64 * LDH];  // [n][k] = W2[k][n]
    __shared__ __align__(16) __bf16 sPWt[64 * LDH];  // [n][k] = pwW[k][n]
    __shared__ __align__(16) __bf16 sHY[BM * LDH];   // h then reused for y
    __shared__ float sW1[3 * 64];
    __shared__ float sb1[64], sb2[64], sdww[64], sdwb[64], spwb[64], slng[64], slnb[64];

    const int tid = threadIdx.x;
    const int lane = tid & 63;
    const int wave = tid >> 6;
    const int block0 = blockIdx.x * BM;

    // ---- stage params + transposed bf16 weights ----
    if (tid < 192) sW1[tid] = W1[tid];
    if (tid < 64) {
        sb1[tid] = b1[tid];  sb2[tid] = b2[tid];
        sdww[tid] = dww[tid]; sdwb[tid] = dwb[tid];
        spwb[tid] = pwb[tid]; slng[tid] = lng[tid]; slnb[tid] = lnb[tid];
    }
    for (int e = tid; e < 64 * 64; e += 256) {
        int k = e >> 6, n = e & 63;
        sW2t[n * LDH + k] = (__bf16)W2[e];
        sPWt[n * LDH + k] = (__bf16)pwW[e];
    }
    __syncthreads();

    // ---- fp32 MLP 3->64 with exact-erf GELU, write h (bf16) in A-layout ----
    {
        int p = tid & (BM - 1);
        int half = tid >> 7;  // 0 or 1: which 32 hidden units
        int gp = block0 + p;
        float d0 = 0.f, d1 = 0.f, d2 = 0.f;
        if (gp < NPTS) {
            int pid = ids[gp];
            float4 a = ((const float4*)acc4)[pid];
            float invc = 1.0f / fmaxf(a.w, 1.0f);
            d0 = coord[3 * gp + 0] - a.x * invc;
            d1 = coord[3 * gp + 1] - a.y * invc;
            d2 = coord[3 * gp + 2] - a.z * invc;
        }
        #pragma unroll
        for (int j0 = 0; j0 < 32; j0 += 8) {
            bf16x8 pack;
            #pragma unroll
            for (int u = 0; u < 8; ++u) {
                int j = half * 32 + j0 + u;
                float v = sb1[j] + d0 * sW1[j] + d1 * sW1[64 + j] + d2 * sW1[128 + j];
                v = 0.5f * v * (1.0f + erff(v * 0.70710678118654752f));
                pack[u] = (__bf16)v;
            }
            *(bf16x8*)&sHY[p * LDH + half * 32 + j0] = pack;
        }
    }
    __syncthreads();

    const int q = lane >> 4;   // quad 0..3
    const int ln = lane & 15;  // lane-in-quad

    // ---- GEMM1: pos = h @ W2 (rows wave*32..+32, cols 0..63) ----
    f32x4 acc[2][4];
    #pragma unroll
    for (int m = 0; m < 2; ++m)
        #pragma unroll
        for (int t = 0; t < 4; ++t)
            acc[m][t] = (f32x4){0.f, 0.f, 0.f, 0.f};

    #pragma unroll
    for (int ks = 0; ks < 2; ++ks) {
        bf16x8 af[2], bfr[4];
        #pragma unroll
        for (int m = 0; m < 2; ++m) {
            int row = wave * 32 + m * 16 + ln;
            af[m] = *(const bf16x8*)&sHY[row * LDH + ks * 32 + q * 8];
        }
        #pragma unroll
        for (int t = 0; t < 4; ++t) {
            int col = t * 16 + ln;
            bfr[t] = *(const bf16x8*)&sW2t[col * LDH + ks * 32 + q * 8];
        }
        #pragma unroll
        for (int m = 0; m < 2; ++m)
            #pragma unroll
            for (int t = 0; t < 4; ++t)
                acc[m][t] = __builtin_amdgcn_mfma_f32_16x16x32_bf16(af[m], bfr[t], acc[m][t], 0, 0, 0);
    }
    __syncthreads();  // all waves done reading sHY

    // ---- epilogue: out = x + pos + b2; y = out*dww + dwb -> bf16 to sHY ----
    #pragma unroll
    for (int m = 0; m < 2; ++m) {
        int rbase = wave * 32 + m * 16 + q * 4;
        #pragma unroll
        for (int t = 0; t < 4; ++t) {
            int c = t * 16 + ln;
            #pragma unroll
            for (int r4 = 0; r4 < 4; ++r4) {
                int r = rbase + r4;
                int gp = block0 + r;
                float xv = (gp < NPTS) ? x[gp * 64 + c] : 0.0f;
                float o = xv + acc[m][t][r4] + sb2[c];
                float yv = o * sdww[c] + sdwb[c];
                sHY[r * LDH + c] = (__bf16)yv;
            }
        }
    }
    __syncthreads();

    // ---- GEMM2: o = y @ pw_W ----
    #pragma unroll
    for (int m = 0; m < 2; ++m)
        #pragma unroll
        for (int t = 0; t < 4; ++t)
            acc[m][t] = (f32x4){0.f, 0.f, 0.f, 0.f};

    #pragma unroll
    for (int ks = 0; ks < 2; ++ks) {
        bf16x8 af[2], bfr[4];
        #pragma unroll
        for (int m = 0; m < 2; ++m) {
            int row = wave * 32 + m * 16 + ln;
            af[m] = *(const bf16x8*)&sHY[row * LDH + ks * 32 + q * 8];
        }
        #pragma unroll
        for (int t = 0; t < 4; ++t) {
            int col = t * 16 + ln;
            bfr[t] = *(const bf16x8*)&sPWt[col * LDH + ks * 32 + q * 8];
        }
        #pragma unroll
        for (int m = 0; m < 2; ++m)
            #pragma unroll
            for (int t = 0; t < 4; ++t)
                acc[m][t] = __builtin_amdgcn_mfma_f32_16x16x32_bf16(af[m], bfr[t], acc[m][t], 0, 0, 0);
    }

    // ---- LayerNorm fully in registers (quad = 16 lanes hold one row group) ----
    #pragma unroll
    for (int m = 0; m < 2; ++m) {
        int rbase = wave * 32 + m * 16 + q * 4;
        // add pointwise bias first
        #pragma unroll
        for (int t = 0; t < 4; ++t) {
            int c = t * 16 + ln;
            #pragma unroll
            for (int r4 = 0; r4 < 4; ++r4) acc[m][t][r4] += spwb[c];
        }
        float s[4], ss[4];
        #pragma unroll
        for (int r4 = 0; r4 < 4; ++r4) {
            float a = 0.f, b = 0.f;
            #pragma unroll
            for (int t = 0; t < 4; ++t) {
                float v = acc[m][t][r4];
                a += v; b += v * v;
            }
            s[r4] = a; ss[r4] = b;
        }
        #pragma unroll
        for (int mask = 8; mask >= 1; mask >>= 1) {
            #pragma unroll
            for (int r4 = 0; r4 < 4; ++r4) {
                s[r4] += __shfl_xor(s[r4], mask);
                ss[r4] += __shfl_xor(ss[r4], mask);
            }
        }
        float mu[4], rs[4];
        #pragma unroll
        for (int r4 = 0; r4 < 4; ++r4) {
            mu[r4] = s[r4] * (1.0f / 64.0f);
            float var = ss[r4] * (1.0f / 64.0f) - mu[r4] * mu[r4];
            rs[r4] = rsqrtf(var + 1e-5f);
        }
        #pragma unroll
        for (int t = 0; t < 4; ++t) {
            int c = t * 16 + ln;
            #pragma unroll
            for (int r4 = 0; r4 < 4; ++r4) {
                int gp = block0 + rbase + r4;
                if (gp < NPTS) {
                    float v = (acc[m][t][r4] - mu[r4]) * rs[r4] * slng[c] + slnb[c];
                    out[gp * 64 + c] = v;
                }
            }
        }
    }
}

extern "C" void kernel_launch(void* const* d_in, const int* in_sizes, int n_in,
                              void* d_out, int out_size, void* d_ws, size_t ws_size,
                              hipStream_t stream) {
    const float* x     = (const float*)d_in[0];
    const float* coord = (const float*)d_in[1];
    const int*   ids   = (const int*)d_in[2];
    const float* W1    = (const float*)d_in[3];
    const float* b1    = (const float*)d_in[4];
    const float* W2    = (const float*)d_in[5];
    const float* b2    = (const float*)d_in[6];
    const float* dww   = (const float*)d_in[7];
    const float* dwb   = (const float*)d_in[8];
    const float* pwW   = (const float*)d_in[9];
    const float* pwb   = (const float*)d_in[10];
    const float* lng   = (const float*)d_in[11];
    const float* lnb   = (const float*)d_in[12];
    float* outp = (float*)d_out;
    float* acc4 = (float*)d_ws;

    hipMemsetAsync(d_ws, 0, NPATCH * 4 * sizeof(float), stream);
    patch_accum<<<(NPTS + 255) / 256, 256, 0, stream>>>(coord, ids, acc4);
    cpe_main<<<(NPTS + BM - 1) / BM, 256, 0, stream>>>(
        x, coord, ids, W1, b1, W2, b2, dww, dwb, pwW, pwb, lng, lnb, acc4, outp);
}